// Round 10
// baseline (302.030 us; speedup 1.0000x reference)
//
#include <hip/hip_runtime.h>
#include <math.h>

typedef __bf16 bf16;
typedef __bf16 bf16x8 __attribute__((ext_vector_type(8)));
typedef float  f32x16 __attribute__((ext_vector_type(16)));

#define NATOMS 50000
#define NEDGES 400000
#define NG 10
#define NZ 100
#define BE 128                 /* edges per k_edge block (4 waves x 32) */
#define NBLK 3225              /* >= ceil((400000 + 100*127)/128) */
#define NLDSC 11               /* PT chunks in LDS; +1 Hj slot = 48 KB -> 3 blocks/CU */
#define DELTA_F 0.10204081632653061f          /* 5/49 */

// ---- d_out layout (float elements) ----
#define OUT_VEC   6400000LL
#define OUT_Z     25600000LL
#define OUT_POS   25650000LL
#define OUT_BATCH 25800000LL

// ---- workspace layout (float units) ----
#define WS_M1   0LL
#define WS_M0   65536LL
#define WS_C0   78336LL
#define WS_M2   78592LL
#define WS_CC   80128LL
#define WS_AI   80384LL
#define WS_AJ   105984LL
#define WS_GI   131584LL
#define WS_GJ   157184LL
#define WS_HI   182784LL          /* 100*10*128 f32 */
#define WS_HJB  310784LL          /* 100*2048 bf16 = 102400 fu */
#define WS_PTC  413184LL          /* 37*2048 bf16 = 37888 fu */
#define WS_GT   451072LL          /* [412800][12] f32 */
#define WS_EV   5404672LL         /* [412800][4] f32 */
#define WS_EO   7055872LL         /* [412800][128] bf16 = 26419200 fu */
#define WS_I    33475072LL        /* int region */
// int region offsets (ints)
#define I_CNT   0
#define I_START 50000
#define I_CUR   100000
#define I_CSR   150000
#define I_ZB    550000
#define I_ZC    550128
#define I_B2Z   550256            /* 3232 ints */
#define I_BSUM  553488            /* 64 */
#define I_BOFF  553552            /* 64 */
#define I_PERM  553616            /* NBLK*128 = 412800 ints */

// ---------------- helpers ----------------

__device__ __forceinline__ float dot256(const float* __restrict__ a,
                                        const float* __restrict__ B, int c)
{
    float s0 = 0, s1 = 0, s2 = 0, s3 = 0;
    for (int k = 0; k < 256; k += 4) {
        s0 += a[k]     * B[(k)     * 256 + c];
        s1 += a[k + 1] * B[(k + 1) * 256 + c];
        s2 += a[k + 2] * B[(k + 2) * 256 + c];
        s3 += a[k + 3] * B[(k + 3) * 256 + c];
    }
    return (s0 + s1) + (s2 + s3);
}

__device__ __forceinline__ unsigned pack2bf(float a, float b)
{
    union { __bf16 h; unsigned short u; } ca, cb;
    ca.h = (__bf16)a; cb.h = (__bf16)b;
    return (unsigned)ca.u | ((unsigned)cb.u << 16);
}

// ---------------- fused precompute A: dt/emb GEMVs + histograms + tail ------

__global__ void kA(const float* __restrict__ W_dt, const float* __restrict__ b_dt,
                   const float* __restrict__ b_gamma, const float* __restrict__ Wg3,
                   float* __restrict__ M1, float* __restrict__ M2, float* __restrict__ cc,
                   const float* __restrict__ emb,
                   const float* __restrict__ W_ai, const float* __restrict__ b_ai,
                   const float* __restrict__ W_aj, const float* __restrict__ b_aj,
                   float* __restrict__ Ai, float* __restrict__ Aj,
                   const int* __restrict__ esrc, const int* __restrict__ edst,
                   const int* __restrict__ z,
                   int* __restrict__ cnt, int* __restrict__ zbins,
                   const float* __restrict__ pos, const int* __restrict__ batch,
                   float* __restrict__ out)
{
    const int r = blockIdx.x, tid = threadIdx.x;
    if (r < 263) {
        const float* a = (r < 262) ? (W_dt + (size_t)r * 256) : b_dt;
        float res = dot256(a, Wg3, tid);
        if (r == 262) res += b_gamma[tid];
        if (r < 256) M1[(size_t)r * 256 + tid] = res;
        else if (r < 262) M2[(size_t)(r - 256) * 256 + tid] = res;
        else cc[tid] = res;
    } else if (r < 463) {
        const int r2 = r - 263;
        const int zz = r2 % 100, side = r2 / 100;
        float res = dot256(emb + (size_t)zz * 256, side ? W_aj : W_ai, tid)
                  + (side ? b_aj[tid] : b_ai[tid]);
        (side ? Aj : Ai)[(size_t)zz * 256 + tid] = res;
    } else if (r < 2026) {
        __shared__ int h[NZ];
        for (int i = tid; i < NZ; i += 256) h[i] = 0;
        __syncthreads();
        const int e = (r - 463) * 256 + tid;
        if (e < NEDGES) {
            atomicAdd(&cnt[esrc[e]], 1);
            atomicAdd(&h[z[edst[e]]], 1);
        }
        __syncthreads();
        for (int i = tid; i < NZ; i += 256) if (h[i]) atomicAdd(&zbins[i], h[i]);
    } else {
        const int i = (r - 2026) * 256 + tid;
        if (i < NATOMS) {
            out[OUT_Z + i] = (float)z[i];
            out[OUT_BATCH + i] = (float)batch[i];
        }
        if (i < 3 * NATOMS) out[OUT_POS + i] = pos[i];
    }
}

// ---------------- fused precompute B: M0/c0 + Gi/Gj ----------------

__global__ void kB(const float* __restrict__ W_dist, const float* __restrict__ b_dist,
                   const float* __restrict__ M1, float* __restrict__ M0, float* __restrict__ c0,
                   const float* __restrict__ Ai, const float* __restrict__ Aj,
                   const float* __restrict__ Wg1, const float* __restrict__ Wg2,
                   float* __restrict__ Gi, float* __restrict__ Gj)
{
    const int r = blockIdx.x, c = threadIdx.x;
    if (r < 51) {
        const float* a = (r < 50) ? (W_dist + (size_t)r * 256) : b_dist;
        float res = dot256(a, M1, c);
        if (r < 50) M0[(size_t)r * 256 + c] = res; else c0[c] = res;
    } else {
        const int r2 = r - 51;
        const int zz = r2 % 100, side = r2 / 100;
        float res = side ? dot256(Aj + (size_t)zz * 256, Wg2, c)
                         : dot256(Ai + (size_t)zz * 256, Wg1, c);
        (side ? Gj : Gi)[(size_t)zz * 256 + c] = res;
    }
}

// ---------------- fused precompute C: H tables + PTc ----------------

__global__ void kC(const float* __restrict__ Gi, const float* __restrict__ Gj,
                   const float* __restrict__ Wexp,
                   float* __restrict__ Hi, bf16* __restrict__ Hjb,
                   const float* __restrict__ M0, const float* __restrict__ M2,
                   const float* __restrict__ c0, const float* __restrict__ cc,
                   const float* __restrict__ b_exp, bf16* __restrict__ PTc)
{
    const int r = blockIdx.x;
    const int f = threadIdx.x;            // 128
    if (r < 1000) {
        const int zz = r / 10, g = r - zz * 10;
        const float* w  = Wexp + (size_t)g * 32768 + f;
        const float* gi = Gi + (size_t)zz * 256;
        const float* gj = Gj + (size_t)zz * 256;
        float a0=0,a1=0,a2=0,a3=0,b0=0,b1=0,b2=0,b3=0;
        for (int k = 0; k < 256; k += 4) {
            const float w0 = w[k*128], w1 = w[(k+1)*128], w2 = w[(k+2)*128], w3 = w[(k+3)*128];
            a0 += gi[k]*w0;   a1 += gi[k+1]*w1; a2 += gi[k+2]*w2; a3 += gi[k+3]*w3;
            b0 += gj[k]*w0;   b1 += gj[k+1]*w1; b2 += gj[k+2]*w2; b3 += gj[k+3]*w3;
        }
        Hi[(size_t)r * 128 + f] = (a0+a1)+(a2+a3);
        Hjb[(size_t)zz * 2048 + (g >> 3) * 1024 + f * 8 + (g & 7)] = (bf16)((b0+b1)+(b2+b3));
    } else {
        const int b = r - 1000;           // 0..591
        const int ck = b >> 4, kl = b & 15;
        const int k = ck * 16 + kl;
        float val = 0.f;
        if (k < 580) {
            const float* arow; int g; float bias = 0.f;
            if (k < 500)      { g = k / 50; arow = M0 + (size_t)(k - g * 50) * 256; }
            else if (k < 560) { const int jj = k - 500; g = jj / 6; arow = M2 + (size_t)(jj - g * 6) * 256; }
            else if (k < 570) { g = k - 560; arow = c0; }
            else              { g = k - 570; arow = cc; bias = b_exp[g * 128 + f]; }
            const float* w = Wexp + (size_t)g * 32768 + f;
            float s0=0,s1=0,s2=0,s3=0;
            for (int c2 = 0; c2 < 256; c2 += 4) {
                s0 += arow[c2]   * w[(c2)   * 128];
                s1 += arow[c2+1] * w[(c2+1) * 128];
                s2 += arow[c2+2] * w[(c2+2) * 128];
                s3 += arow[c2+3] * w[(c2+3) * 128];
            }
            val = (s0+s1)+(s2+s3) + bias;
        }
        PTc[(size_t)ck * 2048 + (kl >> 3) * 1024 + f * 8 + (kl & 7)] = (bf16)val;
    }
}

// ---------------- hierarchical scans (wide, latency-tolerant) ----------------

__global__ void kD1(const int* __restrict__ cnt, int* __restrict__ startp,
                    int* __restrict__ bsum)
{
    __shared__ int part[1024];
    const int tid = threadIdx.x;
    const int i = blockIdx.x * 1024 + tid;
    const int v = (i < NATOMS) ? cnt[i] : 0;
    part[tid] = v;
    __syncthreads();
    for (int off = 1; off < 1024; off <<= 1) {
        int t2 = part[tid];
        if (tid >= off) t2 += part[tid - off];
        __syncthreads();
        part[tid] = t2;
        __syncthreads();
    }
    if (i < NATOMS) startp[i] = part[tid] - v;
    if (tid == 1023) bsum[blockIdx.x] = part[1023];
}

__global__ void kD2(const int* __restrict__ bsum, int* __restrict__ boffs,
                    const int* __restrict__ zbins, int* __restrict__ zcursor,
                    int* __restrict__ blk2z)
{
    __shared__ int sc[256];
    const int tid = threadIdx.x;
    // phase 1: scan 49 block sums
    const int v = (tid < 49) ? bsum[tid] : 0;
    sc[tid] = v;
    __syncthreads();
    for (int off = 1; off < 64; off <<= 1) {
        int t2 = sc[tid];
        if (tid >= off) t2 += sc[tid - off];
        __syncthreads();
        sc[tid] = t2;
        __syncthreads();
    }
    if (tid < 49) boffs[tid] = sc[tid] - v;
    __syncthreads();
    // phase 2: scan padded z bins (pad each bucket to BE=128)
    const int pz = (tid < NZ) ? (((zbins[tid] + 127) >> 7) << 7) : 0;
    sc[tid] = pz;
    __syncthreads();
    for (int off = 1; off < 128; off <<= 1) {
        int t2 = sc[tid];
        if (tid >= off) t2 += sc[tid - off];
        __syncthreads();
        sc[tid] = t2;
        __syncthreads();
    }
    if (tid < NZ) {
        const int st = sc[tid] - pz;
        zcursor[tid] = st;
        for (int b = (st >> 7); b < (sc[tid] >> 7); ++b) blk2z[b] = tid;
    }
}

__global__ void kD3(const int* __restrict__ boffs, int* __restrict__ startp,
                    int* __restrict__ cursor)
{
    const int i = blockIdx.x * 1024 + threadIdx.x;
    if (i < NATOMS) {
        const int s2 = startp[i] + boffs[blockIdx.x];
        startp[i] = s2;
        cursor[i] = s2;
    }
}

// ---------------- privatized bucket fill (z-sort scatter + src CSR fill) ----
#define ZF_EPB 1024
__global__ void __launch_bounds__(256) k_zfill(
    const int* __restrict__ edst, const int* __restrict__ z,
    const int* __restrict__ esrc,
    int* __restrict__ zcursor, int* __restrict__ cursor,
    int* __restrict__ perm, int* __restrict__ csr)
{
    __shared__ int h[NZ];
    __shared__ int base[NZ];
    const int t = threadIdx.x;
    for (int i = t; i < NZ; i += 256) h[i] = 0;
    __syncthreads();
    const int e0 = blockIdx.x * ZF_EPB;
    int rank[4], zb[4];
#pragma unroll
    for (int k2 = 0; k2 < 4; ++k2) {
        const int e = e0 + t + k2 * 256;
        if (e < NEDGES) { zb[k2] = z[edst[e]]; rank[k2] = atomicAdd(&h[zb[k2]], 1); }
        else zb[k2] = -1;
    }
    __syncthreads();
    for (int i = t; i < NZ; i += 256) base[i] = h[i] ? atomicAdd(&zcursor[i], h[i]) : 0;
    __syncthreads();
#pragma unroll
    for (int k2 = 0; k2 < 4; ++k2) {
        if (zb[k2] >= 0) {
            const int e = e0 + t + k2 * 256;
            const int pos = base[zb[k2]] + rank[k2];
            perm[pos] = e;
            const int p2 = atomicAdd(&cursor[esrc[e]], 1);
            csr[p2] = pos;
        }
    }
}

// ---------------- MFMA edge kernel: barrier-free hybrid LDS/L2 B ------------

__device__ __forceinline__ float coeff(int k, const unsigned* Gp, const float* gate,
                                       const float* sv, float C)
{
    if (k < 500) {
        const int g = k / 50, rb = k - g * 50;
        const unsigned w = Gp[rb >> 1];
        const unsigned bits = (rb & 1) ? (w & 0xffff0000u) : (w << 16);
        return gate[g] * __uint_as_float(bits);
    } else if (k < 560) {
        const int jj = k - 500;
        return gate[jj / 6] * sv[jj - (jj / 6) * 6];
    } else if (k < 570) {
        return C * gate[k - 560];
    } else if (k < 580) {
        return gate[k - 570];
    }
    return 0.0f;
}

__global__ void __launch_bounds__(256, 3) k_edge(
    const float* __restrict__ edge_vec,
    const int* __restrict__ perm, const int* __restrict__ blk2z,
    const float* __restrict__ tpar,
    const bf16* __restrict__ PTc, const bf16* __restrict__ Hjb,
    float* __restrict__ gates_ws, float* __restrict__ evb, bf16* __restrict__ eo)
{
    __shared__ __align__(16) bf16 Bs[(NLDSC + 1) * 2048];   // 49152 B -> 3 blocks/CU

    const int t    = threadIdx.x;
    const int wid  = t >> 6;
    const int lane = t & 63;
    const int er   = lane & 31;
    const int kh   = lane >> 5;
    const bool khb = (kh != 0);
    const int base = blockIdx.x * BE;
    const int pid  = base + wid * 32 + er;

    if (perm[base] < 0) return;                 // all-dummy block (uniform)

    const int zb  = blk2z[blockIdx.x];
    const int eid = perm[pid];

    // ---- stage LDS chunks (loads first; latency hides under scalar math) ----
    const float4* PTc4 = (const float4*)PTc;
    float4 stg[NLDSC];
#pragma unroll
    for (int i = 0; i < NLDSC; ++i) stg[i] = PTc4[t + i * 256];
    const float4 hv = ((const float4*)(Hjb + (size_t)zb * 2048))[t];

    // ---- per-edge scalars ----
    float gate[NG], sv[6];
    float d = 1.0f, C = 0.0f, vx = 0.f, vy = 0.f, vz = 0.f;
    if (eid >= 0) {
        vx = edge_vec[eid * 3]; vy = edge_vec[eid * 3 + 1]; vz = edge_vec[eid * 3 + 2];
        d = sqrtf(vx * vx + vy * vy + vz * vz);
        C = (d < 5.0f) ? 0.5f * (__cosf(d * 0.6283185307179586f) + 1.0f) : 0.0f;
        float m = -3.0e38f;
#pragma unroll
        for (int g = 0; g < NG; ++g) {
            float r = 1.0f / fmaxf(fabsf(d - tpar[g]), 1e-8f);
            gate[g] = r; m = fmaxf(m, r);
        }
        float ss = 0.f;
#pragma unroll
        for (int g = 0; g < NG; ++g) { float ex = __expf(gate[g] - m); gate[g] = ex; ss += ex; }
        const float inv = 1.0f / ss;
#pragma unroll
        for (int g = 0; g < NG; ++g) gate[g] *= inv;
        const float d2 = d * d;
        sv[0] = d2; sv[1] = d2 * d; sv[2] = d2 * d2;
        sv[3] = sqrtf(d); sv[4] = __logf(d); sv[5] = d;
    } else {
#pragma unroll
        for (int g = 0; g < NG; ++g) gate[g] = 0.f;
#pragma unroll
        for (int m2 = 0; m2 < 6; ++m2) sv[m2] = 0.f;
    }

    // ---- packed Gaussian table (bf16 pairs, C folded in): 25 VGPRs ----
    unsigned Gp[25];
#pragma unroll
    for (int p = 0; p < 25; ++p) {
        const float t0 = d - (float)(2 * p) * DELTA_F;
        const float t1 = t0 - DELTA_F;
        const float g0 = C * __expf(-48.02f * t0 * t0);
        const float g1 = C * __expf(-48.02f * t1 * t1);
        Gp[p] = pack2bf(g0, g1);
    }

    if (kh == 0 && eid >= 0) {
        float* gw = gates_ws + (size_t)pid * 12;
#pragma unroll
        for (int g = 0; g < NG; ++g) gw[g] = gate[g];
        const float invd = 1.0f / d;
        *(float4*)(evb + (size_t)pid * 4) =
            make_float4(vx * invd, vy * invd, vz * invd, 0.0f);
    }

    // ---- write staged LDS, single barrier ----
    {
        float4* dst = (float4*)Bs;
#pragma unroll
        for (int i = 0; i < NLDSC; ++i) dst[t + i * 256] = stg[i];
        dst[t + NLDSC * 256] = hv;
    }
    __syncthreads();

    f32x16 acc0 = {}, acc1 = {}, acc2 = {}, acc3 = {};
    const int lanoff = kh * 1024 + er * 8;
    const bf16* Lp = Bs + lanoff;
    const bf16* Gb = PTc + lanoff;

#define MFMA4(AV, B0, B1, B2, B3) do { \
        acc0 = __builtin_amdgcn_mfma_f32_32x32x16_bf16(AV, B0, acc0, 0, 0, 0); \
        acc1 = __builtin_amdgcn_mfma_f32_32x32x16_bf16(AV, B1, acc1, 0, 0, 0); \
        acc2 = __builtin_amdgcn_mfma_f32_32x32x16_bf16(AV, B2, acc2, 0, 0, 0); \
        acc3 = __builtin_amdgcn_mfma_f32_32x32x16_bf16(AV, B3, acc3, 0, 0, 0); \
    } while (0)
#define LDB(P, V0, V1, V2, V3) \
        const bf16x8 V0 = *(const bf16x8*)(P); \
        const bf16x8 V1 = *(const bf16x8*)((P) + 256); \
        const bf16x8 V2 = *(const bf16x8*)((P) + 512); \
        const bf16x8 V3 = *(const bf16x8*)((P) + 768);

    // ---- Hj K-step (gate coefficients) ----
    {
        bf16x8 av;
#pragma unroll
        for (int j = 0; j < 8; ++j) {
            const float va = gate[j];
            const float vb = (j < 2) ? gate[8 + j] : 0.0f;
            av[j] = (bf16)(khb ? vb : va);
        }
        LDB(Lp + NLDSC * 2048, b0, b1, b2, b3);
        MFMA4(av, b0, b1, b2, b3);
    }

    // ---- prefetch first two global chunks ----
    bf16x8 c0, c1, c2, c3, n0, n1, n2, n3;
    {
        const bf16* bp = Gb + NLDSC * 2048;
        c0 = *(const bf16x8*)(bp);       c1 = *(const bf16x8*)(bp + 256);
        c2 = *(const bf16x8*)(bp + 512); c3 = *(const bf16x8*)(bp + 768);
    }
    {
        const bf16* bp = Gb + (NLDSC + 1) * 2048;
        n0 = *(const bf16x8*)(bp);       n1 = *(const bf16x8*)(bp + 256);
        n2 = *(const bf16x8*)(bp + 512); n3 = *(const bf16x8*)(bp + 768);
    }

    // ---- LDS chunks, no barriers ----
#pragma unroll
    for (int ks = 0; ks < NLDSC; ++ks) {
        bf16x8 av;
#pragma unroll
        for (int j = 0; j < 8; ++j) {
            const float va = coeff(ks * 16 + j,     Gp, gate, sv, C);
            const float vb = coeff(ks * 16 + 8 + j, Gp, gate, sv, C);
            av[j] = (bf16)(khb ? vb : va);
        }
        LDB(Lp + ks * 2048, b0, b1, b2, b3);
        MFMA4(av, b0, b1, b2, b3);
    }

    // ---- global chunks, depth-2 register prefetch ----
#pragma unroll
    for (int ks = NLDSC; ks < 37; ++ks) {
        const bf16x8 m0 = c0, m1 = c1, m2 = c2, m3 = c3;
        c0 = n0; c1 = n1; c2 = n2; c3 = n3;
        if (ks + 2 <= 36) {
            const bf16* bp = Gb + (size_t)(ks + 2) * 2048;
            n0 = *(const bf16x8*)(bp);       n1 = *(const bf16x8*)(bp + 256);
            n2 = *(const bf16x8*)(bp + 512); n3 = *(const bf16x8*)(bp + 768);
        }
        bf16x8 av;
#pragma unroll
        for (int j = 0; j < 8; ++j) {
            const float va = coeff(ks * 16 + j,     Gp, gate, sv, C);
            const float vb = coeff(ks * 16 + 8 + j, Gp, gate, sv, C);
            av[j] = (bf16)(khb ? vb : va);
        }
        MFMA4(av, m0, m1, m2, m3);
    }
#undef MFMA4
#undef LDB

    // ---- epilogue: block-local rows, bf16 stores ----
    bf16* eor = eo + (size_t)(base + wid * 32) * 128 + er;
#pragma unroll
    for (int r = 0; r < 16; ++r) {
        const int crow = (r & 3) + 8 * (r >> 2) + 4 * kh;
        bf16* p = eor + (size_t)crow * 128;
        p[0]  = (bf16)acc0[r];
        p[32] = (bf16)acc1[r];
        p[64] = (bf16)acc2[r];
        p[96] = (bf16)acc3[r];
    }
}

// ---------------- gather: lane-split gate sums + exact Hi fold ----------

__global__ void __launch_bounds__(256) k_gather(
    const bf16* __restrict__ eo, const float* __restrict__ evb,
    const float* __restrict__ gates_ws,
    const int* __restrict__ startp, const int* __restrict__ cnt,
    const int* __restrict__ csr, const int* __restrict__ zarr,
    const float* __restrict__ Hi, float* __restrict__ out)
{
    __shared__ float gsum[4][48];
    const int wloc = threadIdx.x >> 6;
    const int atom = blockIdx.x * 4 + wloc;
    const int lane = threadIdx.x & 63;
    if (atom >= NATOMS) return;
    const int s = startp[atom], len = cnt[atom];
    const unsigned* eo32 = (const unsigned*)eo;
    const float4* ev4 = (const float4*)evb;

    // lane roles for gate sums: lanes 0..39 own (comp = lane/10, g = lane%10)
    const int comp = lane / 10;
    const int gidx = lane - comp * 10;
    const bool gl = (lane < 40);
    float gacc = 0.0f;

    float a0 = 0, a1 = 0, v00 = 0, v01 = 0, v10 = 0, v11 = 0, v20 = 0, v21 = 0;

#define ACCE(PID, EV, U) do { \
        const float evc = (comp == 1) ? EV.x : (comp == 2) ? EV.y : (comp == 3) ? EV.z : 1.0f; \
        if (gl) gacc += evc * gates_ws[(size_t)(PID) * 12 + gidx]; \
        const float y0 = __uint_as_float((U) << 16); \
        const float y1 = __uint_as_float((U) & 0xffff0000u); \
        a0 += y0; a1 += y1; \
        v00 += EV.x * y0; v01 += EV.x * y1; \
        v10 += EV.y * y0; v11 += EV.y * y1; \
        v20 += EV.z * y0; v21 += EV.z * y1; \
    } while (0)

    int i = 0;
    for (; i + 4 <= len; i += 4) {
        const int p0 = csr[s + i],     p1 = csr[s + i + 1];
        const int p2 = csr[s + i + 2], p3 = csr[s + i + 3];
        const float4 e0 = ev4[p0], e1 = ev4[p1], e2 = ev4[p2], e3 = ev4[p3];
        const unsigned u0 = eo32[(size_t)p0 * 64 + lane];
        const unsigned u1 = eo32[(size_t)p1 * 64 + lane];
        const unsigned u2 = eo32[(size_t)p2 * 64 + lane];
        const unsigned u3 = eo32[(size_t)p3 * 64 + lane];
        ACCE(p0, e0, u0);
        ACCE(p1, e1, u1);
        ACCE(p2, e2, u2);
        ACCE(p3, e3, u3);
    }
    for (; i < len; ++i) {
        const int p0 = csr[s + i];
        const float4 e0 = ev4[p0];
        const unsigned u0 = eo32[(size_t)p0 * 64 + lane];
        ACCE(p0, e0, u0);
    }
#undef ACCE

    if (gl) gsum[wloc][comp * 10 + gidx] = gacc;   // same-wave write->read, no barrier

    const float* Hrow = Hi + (size_t)zarr[atom] * 1280;
#pragma unroll
    for (int g = 0; g < NG; ++g) {
        const float gs = gsum[wloc][g];
        const float e0 = gsum[wloc][10 + g];
        const float e1 = gsum[wloc][20 + g];
        const float e2 = gsum[wloc][30 + g];
        const float2 h2 = *(const float2*)(Hrow + g * 128 + 2 * lane);
        a0  += gs * h2.x;  a1  += gs * h2.y;
        v00 += e0 * h2.x;  v01 += e0 * h2.y;
        v10 += e1 * h2.x;  v11 += e1 * h2.y;
        v20 += e2 * h2.x;  v21 += e2 * h2.y;
    }
    float* ao = out + (size_t)atom * 128;
    *(float2*)(ao + 2 * lane) = make_float2(a0, a1);
    float* vp = out + OUT_VEC + (size_t)atom * 384;
    *(float2*)(vp + 2 * lane)       = make_float2(v00, v01);
    *(float2*)(vp + 128 + 2 * lane) = make_float2(v10, v11);
    *(float2*)(vp + 256 + 2 * lane) = make_float2(v20, v21);
}

// ---------------- launch ----------------

extern "C" void kernel_launch(void* const* d_in, const int* in_sizes, int n_in,
                              void* d_out, int out_size, void* d_ws, size_t ws_size,
                              hipStream_t stream)
{
    const int*   z        = (const int*)d_in[0];
    const float* pos      = (const float*)d_in[1];
    const int*   batch    = (const int*)d_in[2];
    const int*   esrc     = (const int*)d_in[3];
    const int*   edst     = esrc + NEDGES;
    const float* edge_vec = (const float*)d_in[4];
    const float* emb      = (const float*)d_in[5];
    const float* W_dist   = (const float*)d_in[6];
    const float* b_dist   = (const float*)d_in[7];
    const float* W_dt     = (const float*)d_in[8];
    const float* b_dt     = (const float*)d_in[9];
    const float* W_ai     = (const float*)d_in[10];
    const float* b_ai     = (const float*)d_in[11];
    const float* W_aj     = (const float*)d_in[12];
    const float* b_aj     = (const float*)d_in[13];
    const float* W_gamma  = (const float*)d_in[14];
    const float* b_gamma  = (const float*)d_in[15];
    const float* W_exp    = (const float*)d_in[16];
    const float* b_exp    = (const float*)d_in[17];
    const float* tpar     = (const float*)d_in[18];

    float* out = (float*)d_out;
    float* W   = (float*)d_ws;

    const float* Wg1 = W_gamma;
    const float* Wg2 = W_gamma + 256 * 256;
    const float* Wg3 = W_gamma + 512 * 256;

    float* M1 = W + WS_M1;
    float* M0 = W + WS_M0;
    float* c0 = W + WS_C0;
    float* M2 = W + WS_M2;
    float* cc = W + WS_CC;
    float* Ai = W + WS_AI;
    float* Aj = W + WS_AJ;
    float* Gi = W + WS_GI;
    float* Gj = W + WS_GJ;
    float* Hi = W + WS_HI;
    bf16*  Hjb = (bf16*)(W + WS_HJB);
    bf16*  PTc = (bf16*)(W + WS_PTC);
    float* gates = W + WS_GT;
    float* evb   = W + WS_EV;
    bf16*  eo    = (bf16*)(W + WS_EO);
    int*   I     = (int*)(W + WS_I);
    int* cnt    = I + I_CNT;
    int* startp = I + I_START;
    int* cursor = I + I_CUR;
    int* csr    = I + I_CSR;
    int* zbins  = I + I_ZB;
    int* zcur   = I + I_ZC;
    int* b2z    = I + I_B2Z;
    int* bsum   = I + I_BSUM;
    int* boffs  = I + I_BOFF;
    int* perm   = I + I_PERM;

    hipMemsetAsync(cnt, 0, NATOMS * sizeof(int), stream);
    hipMemsetAsync(zbins, 0, 128 * sizeof(int), stream);
    hipMemsetAsync(perm, 0xFF, (size_t)NBLK * BE * sizeof(int), stream);
    hipMemsetAsync(Hjb, 0, 100 * 2048 * sizeof(bf16), stream);

    kA<<<2613, 256, 0, stream>>>(W_dt, b_dt, b_gamma, Wg3, M1, M2, cc,
                                 emb, W_ai, b_ai, W_aj, b_aj, Ai, Aj,
                                 esrc, edst, z, cnt, zbins, pos, batch, out);
    kB<<<251, 256, 0, stream>>>(W_dist, b_dist, M1, M0, c0, Ai, Aj, Wg1, Wg2, Gi, Gj);
    kC<<<1592, 128, 0, stream>>>(Gi, Gj, W_exp, Hi, Hjb, M0, M2, c0, cc, b_exp, PTc);
    kD1<<<49, 1024, 0, stream>>>(cnt, startp, bsum);
    kD2<<<1, 256, 0, stream>>>(bsum, boffs, zbins, zcur, b2z);
    kD3<<<49, 1024, 0, stream>>>(boffs, startp, cursor);
    k_zfill<<<(NEDGES + ZF_EPB - 1) / ZF_EPB, 256, 0, stream>>>(edst, z, esrc, zcur, cursor, perm, csr);

    k_edge<<<NBLK, 256, 0, stream>>>(edge_vec, perm, b2z, tpar, PTc, Hjb, gates, evb, eo);
    k_gather<<<(NATOMS + 3) / 4, 256, 0, stream>>>(eo, evb, gates, startp, cnt, csr, z, Hi, out);
}

// Round 11
// 259.557 us; speedup vs baseline: 1.1636x; 1.1636x over previous
//
#include <hip/hip_runtime.h>
#include <math.h>

typedef __bf16 bf16;
typedef __bf16 bf16x8 __attribute__((ext_vector_type(8)));
typedef float  f32x16 __attribute__((ext_vector_type(16)));

#define NATOMS 50000
#define NEDGES 400000
#define NG 10
#define NZ 100
#define BE 128                 /* edges per k_edge block (4 waves x 32) */
#define NBLK 3225              /* >= ceil((400000 + 100*127)/128) */
#define NLDSC 14               /* PT chunks in LDS; +1 Hj slot = 60 KB -> 2 blocks/CU */
#define DELTA_F 0.10204081632653061f          /* 5/49 */

// ---- d_out layout (float elements) ----
#define OUT_VEC   6400000LL
#define OUT_Z     25600000LL
#define OUT_POS   25650000LL
#define OUT_BATCH 25800000LL

// ---- workspace layout (float units) ----
#define WS_M1   0LL
#define WS_M0   65536LL
#define WS_C0   78336LL
#define WS_M2   78592LL
#define WS_CC   80128LL
#define WS_AI   80384LL
#define WS_AJ   105984LL
#define WS_GI   131584LL
#define WS_GJ   157184LL
#define WS_HI   182784LL          /* 100*10*128 f32 */
#define WS_HJB  310784LL          /* 100*2048 bf16 = 102400 fu */
#define WS_PTC  413184LL          /* 37*2048 bf16 = 37888 fu */
#define WS_GT   451072LL          /* [412800][12] f32 */
#define WS_EV   5404672LL         /* [412800][4] f32 */
#define WS_EO   7055872LL         /* [412800][128] bf16 = 26419200 fu */
#define WS_I    33475072LL        /* int region */
// int region offsets (ints)
#define I_CNT   0
#define I_START 50000
#define I_CUR   100000
#define I_CSR   150000
#define I_ZB    550000
#define I_ZC    550128
#define I_B2Z   550256            /* 3232 ints */
#define I_BSUM  553488            /* 64 */
#define I_BOFF  553552            /* 64 */
#define I_PERM  553616            /* NBLK*128 = 412800 ints */

// ---------------- helpers ----------------

__device__ __forceinline__ float dot256(const float* __restrict__ a,
                                        const float* __restrict__ B, int c)
{
    float s0 = 0, s1 = 0, s2 = 0, s3 = 0;
    for (int k = 0; k < 256; k += 4) {
        s0 += a[k]     * B[(k)     * 256 + c];
        s1 += a[k + 1] * B[(k + 1) * 256 + c];
        s2 += a[k + 2] * B[(k + 2) * 256 + c];
        s3 += a[k + 3] * B[(k + 3) * 256 + c];
    }
    return (s0 + s1) + (s2 + s3);
}

__device__ __forceinline__ unsigned pack2bf(float a, float b)
{
    union { __bf16 h; unsigned short u; } ca, cb;
    ca.h = (__bf16)a; cb.h = (__bf16)b;
    return (unsigned)ca.u | ((unsigned)cb.u << 16);
}

// ---------------- fused precompute A: dt/emb GEMVs + histograms + tail ------

__global__ void kA(const float* __restrict__ W_dt, const float* __restrict__ b_dt,
                   const float* __restrict__ b_gamma, const float* __restrict__ Wg3,
                   float* __restrict__ M1, float* __restrict__ M2, float* __restrict__ cc,
                   const float* __restrict__ emb,
                   const float* __restrict__ W_ai, const float* __restrict__ b_ai,
                   const float* __restrict__ W_aj, const float* __restrict__ b_aj,
                   float* __restrict__ Ai, float* __restrict__ Aj,
                   const int* __restrict__ esrc, const int* __restrict__ edst,
                   const int* __restrict__ z,
                   int* __restrict__ cnt, int* __restrict__ zbins,
                   const float* __restrict__ pos, const int* __restrict__ batch,
                   float* __restrict__ out)
{
    const int r = blockIdx.x, tid = threadIdx.x;
    if (r < 263) {
        const float* a = (r < 262) ? (W_dt + (size_t)r * 256) : b_dt;
        float res = dot256(a, Wg3, tid);
        if (r == 262) res += b_gamma[tid];
        if (r < 256) M1[(size_t)r * 256 + tid] = res;
        else if (r < 262) M2[(size_t)(r - 256) * 256 + tid] = res;
        else cc[tid] = res;
    } else if (r < 463) {
        const int r2 = r - 263;
        const int zz = r2 % 100, side = r2 / 100;
        float res = dot256(emb + (size_t)zz * 256, side ? W_aj : W_ai, tid)
                  + (side ? b_aj[tid] : b_ai[tid]);
        (side ? Aj : Ai)[(size_t)zz * 256 + tid] = res;
    } else if (r < 2026) {
        __shared__ int h[NZ];
        for (int i = tid; i < NZ; i += 256) h[i] = 0;
        __syncthreads();
        const int e = (r - 463) * 256 + tid;
        if (e < NEDGES) {
            atomicAdd(&cnt[esrc[e]], 1);
            atomicAdd(&h[z[edst[e]]], 1);
        }
        __syncthreads();
        for (int i = tid; i < NZ; i += 256) if (h[i]) atomicAdd(&zbins[i], h[i]);
    } else {
        const int i = (r - 2026) * 256 + tid;
        if (i < NATOMS) {
            out[OUT_Z + i] = (float)z[i];
            out[OUT_BATCH + i] = (float)batch[i];
        }
        if (i < 3 * NATOMS) out[OUT_POS + i] = pos[i];
    }
}

// ---------------- fused precompute B: M0/c0 + Gi/Gj ----------------

__global__ void kB(const float* __restrict__ W_dist, const float* __restrict__ b_dist,
                   const float* __restrict__ M1, float* __restrict__ M0, float* __restrict__ c0,
                   const float* __restrict__ Ai, const float* __restrict__ Aj,
                   const float* __restrict__ Wg1, const float* __restrict__ Wg2,
                   float* __restrict__ Gi, float* __restrict__ Gj)
{
    const int r = blockIdx.x, c = threadIdx.x;
    if (r < 51) {
        const float* a = (r < 50) ? (W_dist + (size_t)r * 256) : b_dist;
        float res = dot256(a, M1, c);
        if (r < 50) M0[(size_t)r * 256 + c] = res; else c0[c] = res;
    } else {
        const int r2 = r - 51;
        const int zz = r2 % 100, side = r2 / 100;
        float res = side ? dot256(Aj + (size_t)zz * 256, Wg2, c)
                         : dot256(Ai + (size_t)zz * 256, Wg1, c);
        (side ? Gj : Gi)[(size_t)zz * 256 + c] = res;
    }
}

// ---------------- fused precompute C: H tables + PTc ----------------

__global__ void kC(const float* __restrict__ Gi, const float* __restrict__ Gj,
                   const float* __restrict__ Wexp,
                   float* __restrict__ Hi, bf16* __restrict__ Hjb,
                   const float* __restrict__ M0, const float* __restrict__ M2,
                   const float* __restrict__ c0, const float* __restrict__ cc,
                   const float* __restrict__ b_exp, bf16* __restrict__ PTc)
{
    const int r = blockIdx.x;
    const int f = threadIdx.x;            // 128
    if (r < 1000) {
        const int zz = r / 10, g = r - zz * 10;
        const float* w  = Wexp + (size_t)g * 32768 + f;
        const float* gi = Gi + (size_t)zz * 256;
        const float* gj = Gj + (size_t)zz * 256;
        float a0=0,a1=0,a2=0,a3=0,b0=0,b1=0,b2=0,b3=0;
        for (int k = 0; k < 256; k += 4) {
            const float w0 = w[k*128], w1 = w[(k+1)*128], w2 = w[(k+2)*128], w3 = w[(k+3)*128];
            a0 += gi[k]*w0;   a1 += gi[k+1]*w1; a2 += gi[k+2]*w2; a3 += gi[k+3]*w3;
            b0 += gj[k]*w0;   b1 += gj[k+1]*w1; b2 += gj[k+2]*w2; b3 += gj[k+3]*w3;
        }
        Hi[(size_t)r * 128 + f] = (a0+a1)+(a2+a3);
        Hjb[(size_t)zz * 2048 + (g >> 3) * 1024 + f * 8 + (g & 7)] = (bf16)((b0+b1)+(b2+b3));
    } else {
        const int b = r - 1000;           // 0..591
        const int ck = b >> 4, kl = b & 15;
        const int k = ck * 16 + kl;
        float val = 0.f;
        if (k < 580) {
            const float* arow; int g; float bias = 0.f;
            if (k < 500)      { g = k / 50; arow = M0 + (size_t)(k - g * 50) * 256; }
            else if (k < 560) { const int jj = k - 500; g = jj / 6; arow = M2 + (size_t)(jj - g * 6) * 256; }
            else if (k < 570) { g = k - 560; arow = c0; }
            else              { g = k - 570; arow = cc; bias = b_exp[g * 128 + f]; }
            const float* w = Wexp + (size_t)g * 32768 + f;
            float s0=0,s1=0,s2=0,s3=0;
            for (int c2 = 0; c2 < 256; c2 += 4) {
                s0 += arow[c2]   * w[(c2)   * 128];
                s1 += arow[c2+1] * w[(c2+1) * 128];
                s2 += arow[c2+2] * w[(c2+2) * 128];
                s3 += arow[c2+3] * w[(c2+3) * 128];
            }
            val = (s0+s1)+(s2+s3) + bias;
        }
        PTc[(size_t)ck * 2048 + (kl >> 3) * 1024 + f * 8 + (kl & 7)] = (bf16)val;
    }
}

// ---------------- hierarchical scans (wide, latency-tolerant) ----------------

__global__ void kD1(const int* __restrict__ cnt, int* __restrict__ startp,
                    int* __restrict__ bsum)
{
    __shared__ int part[1024];
    const int tid = threadIdx.x;
    const int i = blockIdx.x * 1024 + tid;
    const int v = (i < NATOMS) ? cnt[i] : 0;
    part[tid] = v;
    __syncthreads();
    for (int off = 1; off < 1024; off <<= 1) {
        int t2 = part[tid];
        if (tid >= off) t2 += part[tid - off];
        __syncthreads();
        part[tid] = t2;
        __syncthreads();
    }
    if (i < NATOMS) startp[i] = part[tid] - v;
    if (tid == 1023) bsum[blockIdx.x] = part[1023];
}

__global__ void kD2(const int* __restrict__ bsum, int* __restrict__ boffs,
                    const int* __restrict__ zbins, int* __restrict__ zcursor,
                    int* __restrict__ blk2z)
{
    __shared__ int sc[256];
    const int tid = threadIdx.x;
    // phase 1: scan 49 block sums
    const int v = (tid < 49) ? bsum[tid] : 0;
    sc[tid] = v;
    __syncthreads();
    for (int off = 1; off < 64; off <<= 1) {
        int t2 = sc[tid];
        if (tid >= off) t2 += sc[tid - off];
        __syncthreads();
        sc[tid] = t2;
        __syncthreads();
    }
    if (tid < 49) boffs[tid] = sc[tid] - v;
    __syncthreads();
    // phase 2: scan padded z bins (pad each bucket to BE=128)
    const int pz = (tid < NZ) ? (((zbins[tid] + 127) >> 7) << 7) : 0;
    sc[tid] = pz;
    __syncthreads();
    for (int off = 1; off < 128; off <<= 1) {
        int t2 = sc[tid];
        if (tid >= off) t2 += sc[tid - off];
        __syncthreads();
        sc[tid] = t2;
        __syncthreads();
    }
    if (tid < NZ) {
        const int st = sc[tid] - pz;
        zcursor[tid] = st;
        for (int b = (st >> 7); b < (sc[tid] >> 7); ++b) blk2z[b] = tid;
    }
}

__global__ void kD3(const int* __restrict__ boffs, int* __restrict__ startp,
                    int* __restrict__ cursor)
{
    const int i = blockIdx.x * 1024 + threadIdx.x;
    if (i < NATOMS) {
        const int s2 = startp[i] + boffs[blockIdx.x];
        startp[i] = s2;
        cursor[i] = s2;
    }
}

// ---------------- privatized bucket fill (z-sort scatter + src CSR fill) ----
#define ZF_EPB 1024
__global__ void __launch_bounds__(256) k_zfill(
    const int* __restrict__ edst, const int* __restrict__ z,
    const int* __restrict__ esrc,
    int* __restrict__ zcursor, int* __restrict__ cursor,
    int* __restrict__ perm, int* __restrict__ csr)
{
    __shared__ int h[NZ];
    __shared__ int base[NZ];
    const int t = threadIdx.x;
    for (int i = t; i < NZ; i += 256) h[i] = 0;
    __syncthreads();
    const int e0 = blockIdx.x * ZF_EPB;
    int rank[4], zb[4];
#pragma unroll
    for (int k2 = 0; k2 < 4; ++k2) {
        const int e = e0 + t + k2 * 256;
        if (e < NEDGES) { zb[k2] = z[edst[e]]; rank[k2] = atomicAdd(&h[zb[k2]], 1); }
        else zb[k2] = -1;
    }
    __syncthreads();
    for (int i = t; i < NZ; i += 256) base[i] = h[i] ? atomicAdd(&zcursor[i], h[i]) : 0;
    __syncthreads();
#pragma unroll
    for (int k2 = 0; k2 < 4; ++k2) {
        if (zb[k2] >= 0) {
            const int e = e0 + t + k2 * 256;
            const int pos = base[zb[k2]] + rank[k2];
            perm[pos] = e;
            const int p2 = atomicAdd(&cursor[esrc[e]], 1);
            csr[p2] = pos;
        }
    }
}

// ---------------- MFMA edge kernel: barrier-free hybrid LDS/L2 B ------------

__device__ __forceinline__ float coeff(int k, const unsigned* Gp, const float* gate,
                                       const float* sv, float C)
{
    if (k < 500) {
        const int g = k / 50, rb = k - g * 50;
        const unsigned w = Gp[rb >> 1];
        const unsigned bits = (rb & 1) ? (w & 0xffff0000u) : (w << 16);
        return gate[g] * __uint_as_float(bits);
    } else if (k < 560) {
        const int jj = k - 500;
        return gate[jj / 6] * sv[jj - (jj / 6) * 6];
    } else if (k < 570) {
        return C * gate[k - 560];
    } else if (k < 580) {
        return gate[k - 570];
    }
    return 0.0f;
}

__global__ void __launch_bounds__(256, 2) k_edge(
    const float* __restrict__ edge_vec,
    const int* __restrict__ perm, const int* __restrict__ blk2z,
    const float* __restrict__ tpar,
    const bf16* __restrict__ PTc, const bf16* __restrict__ Hjb,
    float* __restrict__ gates_ws, float* __restrict__ evb, bf16* __restrict__ eo)
{
    __shared__ __align__(16) bf16 Bs[(NLDSC + 1) * 2048];   // 61440 B

    const int t    = threadIdx.x;
    const int wid  = t >> 6;
    const int lane = t & 63;
    const int er   = lane & 31;
    const int kh   = lane >> 5;
    const bool khb = (kh != 0);
    const int base = blockIdx.x * BE;
    const int pid  = base + wid * 32 + er;

    if (perm[base] < 0) return;                 // all-dummy block (uniform)

    const int zb  = blk2z[blockIdx.x];
    const int eid = perm[pid];

    // ---- stage LDS chunks (loads first; latency hides under scalar math) ----
    const float4* PTc4 = (const float4*)PTc;
    float4 stg[NLDSC];
#pragma unroll
    for (int i = 0; i < NLDSC; ++i) stg[i] = PTc4[t + i * 256];
    const float4 hv = ((const float4*)(Hjb + (size_t)zb * 2048))[t];

    // ---- per-edge scalars ----
    float gate[NG], sv[6];
    float d = 1.0f, C = 0.0f, vx = 0.f, vy = 0.f, vz = 0.f;
    if (eid >= 0) {
        vx = edge_vec[eid * 3]; vy = edge_vec[eid * 3 + 1]; vz = edge_vec[eid * 3 + 2];
        d = sqrtf(vx * vx + vy * vy + vz * vz);
        C = (d < 5.0f) ? 0.5f * (__cosf(d * 0.6283185307179586f) + 1.0f) : 0.0f;
        float m = -3.0e38f;
#pragma unroll
        for (int g = 0; g < NG; ++g) {
            float r = 1.0f / fmaxf(fabsf(d - tpar[g]), 1e-8f);
            gate[g] = r; m = fmaxf(m, r);
        }
        float ss = 0.f;
#pragma unroll
        for (int g = 0; g < NG; ++g) { float ex = __expf(gate[g] - m); gate[g] = ex; ss += ex; }
        const float inv = 1.0f / ss;
#pragma unroll
        for (int g = 0; g < NG; ++g) gate[g] *= inv;
        const float d2 = d * d;
        sv[0] = d2; sv[1] = d2 * d; sv[2] = d2 * d2;
        sv[3] = sqrtf(d); sv[4] = __logf(d); sv[5] = d;
    } else {
#pragma unroll
        for (int g = 0; g < NG; ++g) gate[g] = 0.f;
#pragma unroll
        for (int m2 = 0; m2 < 6; ++m2) sv[m2] = 0.f;
    }

    // ---- packed Gaussian table (bf16 pairs, C folded in): 25 VGPRs ----
    unsigned Gp[25];
#pragma unroll
    for (int p = 0; p < 25; ++p) {
        const float t0 = d - (float)(2 * p) * DELTA_F;
        const float t1 = t0 - DELTA_F;
        const float g0 = C * __expf(-48.02f * t0 * t0);
        const float g1 = C * __expf(-48.02f * t1 * t1);
        Gp[p] = pack2bf(g0, g1);
    }

    if (kh == 0 && eid >= 0) {
        float* gw = gates_ws + (size_t)pid * 12;
#pragma unroll
        for (int g = 0; g < NG; ++g) gw[g] = gate[g];
        const float invd = 1.0f / d;
        *(float4*)(evb + (size_t)pid * 4) =
            make_float4(vx * invd, vy * invd, vz * invd, 0.0f);
    }

    // ---- write staged LDS, single barrier ----
    {
        float4* dst = (float4*)Bs;
#pragma unroll
        for (int i = 0; i < NLDSC; ++i) dst[t + i * 256] = stg[i];
        dst[t + NLDSC * 256] = hv;
    }
    __syncthreads();

    f32x16 acc0 = {}, acc1 = {}, acc2 = {}, acc3 = {};
    const int lanoff = kh * 1024 + er * 8;
    const bf16* Lp = Bs + lanoff;
    const bf16* Gb = PTc + lanoff;

#define MFMA4(AV, B0, B1, B2, B3) do { \
        acc0 = __builtin_amdgcn_mfma_f32_32x32x16_bf16(AV, B0, acc0, 0, 0, 0); \
        acc1 = __builtin_amdgcn_mfma_f32_32x32x16_bf16(AV, B1, acc1, 0, 0, 0); \
        acc2 = __builtin_amdgcn_mfma_f32_32x32x16_bf16(AV, B2, acc2, 0, 0, 0); \
        acc3 = __builtin_amdgcn_mfma_f32_32x32x16_bf16(AV, B3, acc3, 0, 0, 0); \
    } while (0)
#define LDB(P, V0, V1, V2, V3) \
        const bf16x8 V0 = *(const bf16x8*)(P); \
        const bf16x8 V1 = *(const bf16x8*)((P) + 256); \
        const bf16x8 V2 = *(const bf16x8*)((P) + 512); \
        const bf16x8 V3 = *(const bf16x8*)((P) + 768);

    // ---- Hj K-step (gate coefficients) ----
    {
        bf16x8 av;
#pragma unroll
        for (int j = 0; j < 8; ++j) {
            const float va = gate[j];
            const float vb = (j < 2) ? gate[8 + j] : 0.0f;
            av[j] = (bf16)(khb ? vb : va);
        }
        LDB(Lp + NLDSC * 2048, b0, b1, b2, b3);
        MFMA4(av, b0, b1, b2, b3);
    }

    // ---- prefetch first two global chunks ----
    bf16x8 c0, c1, c2, c3, n0, n1, n2, n3;
    {
        const bf16* bp = Gb + NLDSC * 2048;
        c0 = *(const bf16x8*)(bp);       c1 = *(const bf16x8*)(bp + 256);
        c2 = *(const bf16x8*)(bp + 512); c3 = *(const bf16x8*)(bp + 768);
    }
    {
        const bf16* bp = Gb + (NLDSC + 1) * 2048;
        n0 = *(const bf16x8*)(bp);       n1 = *(const bf16x8*)(bp + 256);
        n2 = *(const bf16x8*)(bp + 512); n3 = *(const bf16x8*)(bp + 768);
    }

    // ---- LDS chunks, no barriers ----
#pragma unroll
    for (int ks = 0; ks < NLDSC; ++ks) {
        bf16x8 av;
#pragma unroll
        for (int j = 0; j < 8; ++j) {
            const float va = coeff(ks * 16 + j,     Gp, gate, sv, C);
            const float vb = coeff(ks * 16 + 8 + j, Gp, gate, sv, C);
            av[j] = (bf16)(khb ? vb : va);
        }
        LDB(Lp + ks * 2048, b0, b1, b2, b3);
        MFMA4(av, b0, b1, b2, b3);
    }

    // ---- global chunks, depth-2 register prefetch ----
#pragma unroll
    for (int ks = NLDSC; ks < 37; ++ks) {
        const bf16x8 m0 = c0, m1 = c1, m2 = c2, m3 = c3;
        c0 = n0; c1 = n1; c2 = n2; c3 = n3;
        if (ks + 2 <= 36) {
            const bf16* bp = Gb + (size_t)(ks + 2) * 2048;
            n0 = *(const bf16x8*)(bp);       n1 = *(const bf16x8*)(bp + 256);
            n2 = *(const bf16x8*)(bp + 512); n3 = *(const bf16x8*)(bp + 768);
        }
        bf16x8 av;
#pragma unroll
        for (int j = 0; j < 8; ++j) {
            const float va = coeff(ks * 16 + j,     Gp, gate, sv, C);
            const float vb = coeff(ks * 16 + 8 + j, Gp, gate, sv, C);
            av[j] = (bf16)(khb ? vb : va);
        }
        MFMA4(av, m0, m1, m2, m3);
    }
#undef MFMA4
#undef LDB

    // ---- epilogue: block-local rows, bf16 stores ----
    bf16* eor = eo + (size_t)(base + wid * 32) * 128 + er;
#pragma unroll
    for (int r = 0; r < 16; ++r) {
        const int crow = (r & 3) + 8 * (r >> 2) + 4 * kh;
        bf16* p = eor + (size_t)crow * 128;
        p[0]  = (bf16)acc0[r];
        p[32] = (bf16)acc1[r];
        p[64] = (bf16)acc2[r];
        p[96] = (bf16)acc3[r];
    }
}

// ---------------- gather: lane-split gate sums + exact Hi fold ----------

__global__ void __launch_bounds__(256) k_gather(
    const bf16* __restrict__ eo, const float* __restrict__ evb,
    const float* __restrict__ gates_ws,
    const int* __restrict__ startp, const int* __restrict__ cnt,
    const int* __restrict__ csr, const int* __restrict__ zarr,
    const float* __restrict__ Hi, float* __restrict__ out)
{
    __shared__ float gsum[4][48];
    const int wloc = threadIdx.x >> 6;
    const int atom = blockIdx.x * 4 + wloc;
    const int lane = threadIdx.x & 63;
    if (atom >= NATOMS) return;
    const int s = startp[atom], len = cnt[atom];
    const unsigned* eo32 = (const unsigned*)eo;
    const float4* ev4 = (const float4*)evb;

    // lane roles for gate sums: lanes 0..39 own (comp = lane/10, g = lane%10)
    const int comp = lane / 10;
    const int gidx = lane - comp * 10;
    const bool gl = (lane < 40);
    float gacc = 0.0f;

    float a0 = 0, a1 = 0, v00 = 0, v01 = 0, v10 = 0, v11 = 0, v20 = 0, v21 = 0;

#define ACCE(PID, EV, U) do { \
        const float evc = (comp == 1) ? EV.x : (comp == 2) ? EV.y : (comp == 3) ? EV.z : 1.0f; \
        if (gl) gacc += evc * gates_ws[(size_t)(PID) * 12 + gidx]; \
        const float y0 = __uint_as_float((U) << 16); \
        const float y1 = __uint_as_float((U) & 0xffff0000u); \
        a0 += y0; a1 += y1; \
        v00 += EV.x * y0; v01 += EV.x * y1; \
        v10 += EV.y * y0; v11 += EV.y * y1; \
        v20 += EV.z * y0; v21 += EV.z * y1; \
    } while (0)

    int i = 0;
    for (; i + 4 <= len; i += 4) {
        const int p0 = csr[s + i],     p1 = csr[s + i + 1];
        const int p2 = csr[s + i + 2], p3 = csr[s + i + 3];
        const float4 e0 = ev4[p0], e1 = ev4[p1], e2 = ev4[p2], e3 = ev4[p3];
        const unsigned u0 = eo32[(size_t)p0 * 64 + lane];
        const unsigned u1 = eo32[(size_t)p1 * 64 + lane];
        const unsigned u2 = eo32[(size_t)p2 * 64 + lane];
        const unsigned u3 = eo32[(size_t)p3 * 64 + lane];
        ACCE(p0, e0, u0);
        ACCE(p1, e1, u1);
        ACCE(p2, e2, u2);
        ACCE(p3, e3, u3);
    }
    for (; i < len; ++i) {
        const int p0 = csr[s + i];
        const float4 e0 = ev4[p0];
        const unsigned u0 = eo32[(size_t)p0 * 64 + lane];
        ACCE(p0, e0, u0);
    }
#undef ACCE

    if (gl) gsum[wloc][comp * 10 + gidx] = gacc;   // same-wave write->read, no barrier

    const float* Hrow = Hi + (size_t)zarr[atom] * 1280;
#pragma unroll
    for (int g = 0; g < NG; ++g) {
        const float gs = gsum[wloc][g];
        const float e0 = gsum[wloc][10 + g];
        const float e1 = gsum[wloc][20 + g];
        const float e2 = gsum[wloc][30 + g];
        const float2 h2 = *(const float2*)(Hrow + g * 128 + 2 * lane);
        a0  += gs * h2.x;  a1  += gs * h2.y;
        v00 += e0 * h2.x;  v01 += e0 * h2.y;
        v10 += e1 * h2.x;  v11 += e1 * h2.y;
        v20 += e2 * h2.x;  v21 += e2 * h2.y;
    }
    float* ao = out + (size_t)atom * 128;
    *(float2*)(ao + 2 * lane) = make_float2(a0, a1);
    float* vp = out + OUT_VEC + (size_t)atom * 384;
    *(float2*)(vp + 2 * lane)       = make_float2(v00, v01);
    *(float2*)(vp + 128 + 2 * lane) = make_float2(v10, v11);
    *(float2*)(vp + 256 + 2 * lane) = make_float2(v20, v21);
}

// ---------------- launch ----------------

extern "C" void kernel_launch(void* const* d_in, const int* in_sizes, int n_in,
                              void* d_out, int out_size, void* d_ws, size_t ws_size,
                              hipStream_t stream)
{
    const int*   z        = (const int*)d_in[0];
    const float* pos      = (const float*)d_in[1];
    const int*   batch    = (const int*)d_in[2];
    const int*   esrc     = (const int*)d_in[3];
    const int*   edst     = esrc + NEDGES;
    const float* edge_vec = (const float*)d_in[4];
    const float* emb      = (const float*)d_in[5];
    const float* W_dist   = (const float*)d_in[6];
    const float* b_dist   = (const float*)d_in[7];
    const float* W_dt     = (const float*)d_in[8];
    const float* b_dt     = (const float*)d_in[9];
    const float* W_ai     = (const float*)d_in[10];
    const float* b_ai     = (const float*)d_in[11];
    const float* W_aj     = (const float*)d_in[12];
    const float* b_aj     = (const float*)d_in[13];
    const float* W_gamma  = (const float*)d_in[14];
    const float* b_gamma  = (const float*)d_in[15];
    const float* W_exp    = (const float*)d_in[16];
    const float* b_exp    = (const float*)d_in[17];
    const float* tpar     = (const float*)d_in[18];

    float* out = (float*)d_out;
    float* W   = (float*)d_ws;

    const float* Wg1 = W_gamma;
    const float* Wg2 = W_gamma + 256 * 256;
    const float* Wg3 = W_gamma + 512 * 256;

    float* M1 = W + WS_M1;
    float* M0 = W + WS_M0;
    float* c0 = W + WS_C0;
    float* M2 = W + WS_M2;
    float* cc = W + WS_CC;
    float* Ai = W + WS_AI;
    float* Aj = W + WS_AJ;
    float* Gi = W + WS_GI;
    float* Gj = W + WS_GJ;
    float* Hi = W + WS_HI;
    bf16*  Hjb = (bf16*)(W + WS_HJB);
    bf16*  PTc = (bf16*)(W + WS_PTC);
    float* gates = W + WS_GT;
    float* evb   = W + WS_EV;
    bf16*  eo    = (bf16*)(W + WS_EO);
    int*   I     = (int*)(W + WS_I);
    int* cnt    = I + I_CNT;
    int* startp = I + I_START;
    int* cursor = I + I_CUR;
    int* csr    = I + I_CSR;
    int* zbins  = I + I_ZB;
    int* zcur   = I + I_ZC;
    int* b2z    = I + I_B2Z;
    int* bsum   = I + I_BSUM;
    int* boffs  = I + I_BOFF;
    int* perm   = I + I_PERM;

    hipMemsetAsync(cnt, 0, NATOMS * sizeof(int), stream);
    hipMemsetAsync(zbins, 0, 128 * sizeof(int), stream);
    hipMemsetAsync(perm, 0xFF, (size_t)NBLK * BE * sizeof(int), stream);
    hipMemsetAsync(Hjb, 0, 100 * 2048 * sizeof(bf16), stream);

    kA<<<2613, 256, 0, stream>>>(W_dt, b_dt, b_gamma, Wg3, M1, M2, cc,
                                 emb, W_ai, b_ai, W_aj, b_aj, Ai, Aj,
                                 esrc, edst, z, cnt, zbins, pos, batch, out);
    kB<<<251, 256, 0, stream>>>(W_dist, b_dist, M1, M0, c0, Ai, Aj, Wg1, Wg2, Gi, Gj);
    kC<<<1592, 128, 0, stream>>>(Gi, Gj, W_exp, Hi, Hjb, M0, M2, c0, cc, b_exp, PTc);
    kD1<<<49, 1024, 0, stream>>>(cnt, startp, bsum);
    kD2<<<1, 256, 0, stream>>>(bsum, boffs, zbins, zcur, b2z);
    kD3<<<49, 1024, 0, stream>>>(boffs, startp, cursor);
    k_zfill<<<(NEDGES + ZF_EPB - 1) / ZF_EPB, 256, 0, stream>>>(edst, z, esrc, zcur, cursor, perm, csr);

    k_edge<<<NBLK, 256, 0, stream>>>(edge_vec, perm, b2z, tpar, PTc, Hjb, gates, evb, eo);
    k_gather<<<(NATOMS + 3) / 4, 256, 0, stream>>>(eo, evb, gates, startp, cnt, csr, z, Hi, out);
}

// Round 12
// 252.593 us; speedup vs baseline: 1.1957x; 1.0276x over previous
//
#include <hip/hip_runtime.h>
#include <math.h>

typedef __bf16 bf16;
typedef __bf16 bf16x8 __attribute__((ext_vector_type(8)));
typedef float  f32x16 __attribute__((ext_vector_type(16)));

#define NATOMS 50000
#define NEDGES 400000
#define NG 10
#define NZ 100
#define BE 128                 /* edges per k_edge block (4 waves x 32) */
#define NBLK 3225              /* >= ceil((400000 + 100*127)/128) */
#define NLDSC 14               /* PT chunks in LDS; +1 Hj slot = 60 KB -> 2 blocks/CU */
#define DELTA_F 0.10204081632653061f          /* 5/49 */

// ---- d_out layout (float elements) ----
#define OUT_VEC   6400000LL
#define OUT_Z     25600000LL
#define OUT_POS   25650000LL
#define OUT_BATCH 25800000LL

// ---- workspace layout (float units) ----
#define WS_M1   0LL
#define WS_M0   65536LL
#define WS_C0   78336LL
#define WS_M2   78592LL
#define WS_CC   80128LL
#define WS_AI   80384LL
#define WS_AJ   105984LL
#define WS_GI   131584LL
#define WS_GJ   157184LL
#define WS_HI   182784LL          /* 100*10*128 f32 */
#define WS_HJB  310784LL          /* 100*2048 bf16 = 102400 fu */
#define WS_PTC  413184LL          /* 37*2048 bf16 = 37888 fu */
#define WS_GT   451072LL          /* [412800][12] f32 */
#define WS_EV   5404672LL         /* [412800][4] f32 */
#define WS_EO   7055872LL         /* [412800][128] bf16 = 26419200 fu */
#define WS_I    33475072LL        /* int region */
// int region offsets (ints)
#define I_CNT   0
#define I_START 50000
#define I_CUR   100000
#define I_CSR   150000
#define I_ZB    550000
#define I_ZC    550128
#define I_B2Z   550256            /* 3232 ints */
#define I_BSUM  553488            /* 64 */
#define I_BOFF  553552            /* 64 */
#define I_PERM  553616            /* NBLK*128 = 412800 ints */

// ---------------- helpers ----------------

__device__ __forceinline__ float dot256(const float* __restrict__ a,
                                        const float* __restrict__ B, int c)
{
    float s0 = 0, s1 = 0, s2 = 0, s3 = 0;
    for (int k = 0; k < 256; k += 4) {
        s0 += a[k]     * B[(k)     * 256 + c];
        s1 += a[k + 1] * B[(k + 1) * 256 + c];
        s2 += a[k + 2] * B[(k + 2) * 256 + c];
        s3 += a[k + 3] * B[(k + 3) * 256 + c];
    }
    return (s0 + s1) + (s2 + s3);
}

__device__ __forceinline__ unsigned pack2bf(float a, float b)
{
    union { __bf16 h; unsigned short u; } ca, cb;
    ca.h = (__bf16)a; cb.h = (__bf16)b;
    return (unsigned)ca.u | ((unsigned)cb.u << 16);
}

// ---------------- k0: one clear kernel (replaces 4 memsets) ----------------

__global__ void k0(int* __restrict__ cnt, int* __restrict__ zbins,
                   int* __restrict__ perm, int* __restrict__ hjz)
{
    const int i = blockIdx.x * 256 + threadIdx.x;
    const int stride = gridDim.x * 256;
    for (int j = i; j < NATOMS; j += stride) cnt[j] = 0;
    if (i < 128) zbins[i] = 0;
    for (int j = i; j < NBLK * BE; j += stride) perm[j] = -1;
    for (int j = i; j < 102400; j += stride) hjz[j] = 0;
}

// ---------------- fused precompute A: dt/emb GEMVs + histograms + tail ------

__global__ void kA(const float* __restrict__ W_dt, const float* __restrict__ b_dt,
                   const float* __restrict__ b_gamma, const float* __restrict__ Wg3,
                   float* __restrict__ M1, float* __restrict__ M2, float* __restrict__ cc,
                   const float* __restrict__ emb,
                   const float* __restrict__ W_ai, const float* __restrict__ b_ai,
                   const float* __restrict__ W_aj, const float* __restrict__ b_aj,
                   float* __restrict__ Ai, float* __restrict__ Aj,
                   const int* __restrict__ esrc, const int* __restrict__ edst,
                   const int* __restrict__ z,
                   int* __restrict__ cnt, int* __restrict__ zbins,
                   const float* __restrict__ pos, const int* __restrict__ batch,
                   float* __restrict__ out)
{
    const int r = blockIdx.x, tid = threadIdx.x;
    if (r < 263) {
        const float* a = (r < 262) ? (W_dt + (size_t)r * 256) : b_dt;
        float res = dot256(a, Wg3, tid);
        if (r == 262) res += b_gamma[tid];
        if (r < 256) M1[(size_t)r * 256 + tid] = res;
        else if (r < 262) M2[(size_t)(r - 256) * 256 + tid] = res;
        else cc[tid] = res;
    } else if (r < 463) {
        const int r2 = r - 263;
        const int zz = r2 % 100, side = r2 / 100;
        float res = dot256(emb + (size_t)zz * 256, side ? W_aj : W_ai, tid)
                  + (side ? b_aj[tid] : b_ai[tid]);
        (side ? Aj : Ai)[(size_t)zz * 256 + tid] = res;
    } else if (r < 2026) {
        __shared__ int h[NZ];
        for (int i = tid; i < NZ; i += 256) h[i] = 0;
        __syncthreads();
        const int e = (r - 463) * 256 + tid;
        if (e < NEDGES) {
            atomicAdd(&cnt[esrc[e]], 1);
            atomicAdd(&h[z[edst[e]]], 1);
        }
        __syncthreads();
        for (int i = tid; i < NZ; i += 256) if (h[i]) atomicAdd(&zbins[i], h[i]);
    } else {
        const int i = (r - 2026) * 256 + tid;
        if (i < NATOMS) {
            out[OUT_Z + i] = (float)z[i];
            out[OUT_BATCH + i] = (float)batch[i];
        }
        if (i < 3 * NATOMS) out[OUT_POS + i] = pos[i];
    }
}

// ---------------- kBD1: M0/c0 + Gi/Gj GEMVs, plus kD1 block scan ------------

__global__ void __launch_bounds__(1024) kBD1(
    const float* __restrict__ W_dist, const float* __restrict__ b_dist,
    const float* __restrict__ M1, float* __restrict__ M0, float* __restrict__ c0,
    const float* __restrict__ Ai, const float* __restrict__ Aj,
    const float* __restrict__ Wg1, const float* __restrict__ Wg2,
    float* __restrict__ Gi, float* __restrict__ Gj,
    const int* __restrict__ cnt, int* __restrict__ startp, int* __restrict__ bsum)
{
    const int r = blockIdx.x, tid = threadIdx.x;
    if (r < 251) {
        if (tid < 256) {
            const int c = tid;
            if (r < 51) {
                const float* a = (r < 50) ? (W_dist + (size_t)r * 256) : b_dist;
                float res = dot256(a, M1, c);
                if (r < 50) M0[(size_t)r * 256 + c] = res; else c0[c] = res;
            } else {
                const int r2 = r - 51;
                const int zz = r2 % 100, side = r2 / 100;
                float res = side ? dot256(Aj + (size_t)zz * 256, Wg2, c)
                                 : dot256(Ai + (size_t)zz * 256, Wg1, c);
                (side ? Gj : Gi)[(size_t)zz * 256 + c] = res;
            }
        }
    } else {
        __shared__ int part[1024];
        const int b = r - 251;               // 0..48
        const int i = b * 1024 + tid;
        const int v = (i < NATOMS) ? cnt[i] : 0;
        part[tid] = v;
        __syncthreads();
        for (int off = 1; off < 1024; off <<= 1) {
            int t2 = part[tid];
            if (tid >= off) t2 += part[tid - off];
            __syncthreads();
            part[tid] = t2;
            __syncthreads();
        }
        if (i < NATOMS) startp[i] = part[tid] - v;
        if (tid == 1023) bsum[b] = part[1023];
    }
}

// ---------------- kCD2: H tables (reuse-blocked) + PTc + kD2 scan -----------

__global__ void __launch_bounds__(128) kCD2(
    const float* __restrict__ Gi, const float* __restrict__ Gj,
    const float* __restrict__ Wexp,
    float* __restrict__ Hi, bf16* __restrict__ Hjb,
    const float* __restrict__ M0, const float* __restrict__ M2,
    const float* __restrict__ c0, const float* __restrict__ cc,
    const float* __restrict__ b_exp, bf16* __restrict__ PTc,
    const int* __restrict__ bsum, int* __restrict__ boffs,
    const int* __restrict__ zbins, int* __restrict__ zcursor,
    int* __restrict__ blk2z)
{
    const int r = blockIdx.x;
    const int f = threadIdx.x;            // 0..127
    if (r < 250) {
        // one g, four z's, both sides; W_exp row loaded once per k, 8 FMAs
        __shared__ float Gs[8][256];      // [zi*2+side][k]
        const int g  = r / 25;
        const int z0 = (r % 25) * 4;
        for (int idx = f; idx < 8 * 256; idx += 128) {
            const int row = idx >> 8, k = idx & 255;
            const int zi = row >> 1, side = row & 1;
            Gs[row][k] = side ? Gj[(size_t)(z0 + zi) * 256 + k]
                              : Gi[(size_t)(z0 + zi) * 256 + k];
        }
        __syncthreads();
        const float* w = Wexp + (size_t)g * 32768 + f;
        float acc[8] = {};
#pragma unroll 4
        for (int k = 0; k < 256; ++k) {
            const float wv = w[k * 128];
#pragma unroll
            for (int rr = 0; rr < 8; ++rr) acc[rr] += Gs[rr][k] * wv;
        }
#pragma unroll
        for (int zi = 0; zi < 4; ++zi) {
            const int zz = z0 + zi;
            Hi[((size_t)zz * 10 + g) * 128 + f] = acc[zi * 2];
            Hjb[(size_t)zz * 2048 + (g >> 3) * 1024 + f * 8 + (g & 7)] = (bf16)acc[zi * 2 + 1];
        }
    } else if (r < 842) {
        const int b = r - 250;            // 0..591
        const int ck = b >> 4, kl = b & 15;
        const int k = ck * 16 + kl;
        float val = 0.f;
        if (k < 580) {
            const float* arow; int g; float bias = 0.f;
            if (k < 500)      { g = k / 50; arow = M0 + (size_t)(k - g * 50) * 256; }
            else if (k < 560) { const int jj = k - 500; g = jj / 6; arow = M2 + (size_t)(jj - g * 6) * 256; }
            else if (k < 570) { g = k - 560; arow = c0; }
            else              { g = k - 570; arow = cc; bias = b_exp[g * 128 + f]; }
            const float* w = Wexp + (size_t)g * 32768 + f;
            float s0=0,s1=0,s2=0,s3=0;
            for (int c2 = 0; c2 < 256; c2 += 4) {
                s0 += arow[c2]   * w[(c2)   * 128];
                s1 += arow[c2+1] * w[(c2+1) * 128];
                s2 += arow[c2+2] * w[(c2+2) * 128];
                s3 += arow[c2+3] * w[(c2+3) * 128];
            }
            val = (s0+s1)+(s2+s3) + bias;
        }
        PTc[(size_t)ck * 2048 + (kl >> 3) * 1024 + f * 8 + (kl & 7)] = (bf16)val;
    } else {
        // kD2: scan 49 block sums + padded z bins (128 threads)
        __shared__ int sc[128];
        const int tid = f;
        const int v = (tid < 49) ? bsum[tid] : 0;
        sc[tid] = v;
        __syncthreads();
        for (int off = 1; off < 64; off <<= 1) {
            int t2 = sc[tid];
            if (tid >= off) t2 += sc[tid - off];
            __syncthreads();
            sc[tid] = t2;
            __syncthreads();
        }
        if (tid < 49) boffs[tid] = sc[tid] - v;
        __syncthreads();
        const int pz = (tid < NZ) ? (((zbins[tid] + 127) >> 7) << 7) : 0;
        sc[tid] = pz;
        __syncthreads();
        for (int off = 1; off < 128; off <<= 1) {
            int t2 = sc[tid];
            if (tid >= off) t2 += sc[tid - off];
            __syncthreads();
            sc[tid] = t2;
            __syncthreads();
        }
        for (int b = tid; b < NBLK; b += 128) blk2z[b] = 0;
        __syncthreads();
        if (tid < NZ) {
            const int st = sc[tid] - pz;
            zcursor[tid] = st;
            for (int b = (st >> 7); b < (sc[tid] >> 7); ++b) blk2z[b] = tid;
        }
    }
}

__global__ void kD3(const int* __restrict__ boffs, int* __restrict__ startp,
                    int* __restrict__ cursor)
{
    const int i = blockIdx.x * 1024 + threadIdx.x;
    if (i < NATOMS) {
        const int s2 = startp[i] + boffs[blockIdx.x];
        startp[i] = s2;
        cursor[i] = s2;
    }
}

// ---------------- privatized bucket fill (z-sort scatter + src CSR fill) ----
#define ZF_EPB 1024
__global__ void __launch_bounds__(256) k_zfill(
    const int* __restrict__ edst, const int* __restrict__ z,
    const int* __restrict__ esrc,
    int* __restrict__ zcursor, int* __restrict__ cursor,
    int* __restrict__ perm, int* __restrict__ csr)
{
    __shared__ int h[NZ];
    __shared__ int base[NZ];
    const int t = threadIdx.x;
    for (int i = t; i < NZ; i += 256) h[i] = 0;
    __syncthreads();
    const int e0 = blockIdx.x * ZF_EPB;
    int rank[4], zb[4];
#pragma unroll
    for (int k2 = 0; k2 < 4; ++k2) {
        const int e = e0 + t + k2 * 256;
        if (e < NEDGES) { zb[k2] = z[edst[e]]; rank[k2] = atomicAdd(&h[zb[k2]], 1); }
        else zb[k2] = -1;
    }
    __syncthreads();
    for (int i = t; i < NZ; i += 256) base[i] = h[i] ? atomicAdd(&zcursor[i], h[i]) : 0;
    __syncthreads();
#pragma unroll
    for (int k2 = 0; k2 < 4; ++k2) {
        if (zb[k2] >= 0) {
            const int e = e0 + t + k2 * 256;
            const int pos = base[zb[k2]] + rank[k2];
            perm[pos] = e;
            const int p2 = atomicAdd(&cursor[esrc[e]], 1);
            csr[p2] = pos;
        }
    }
}

// ---------------- MFMA edge kernel: barrier-free hybrid LDS/L2 B ------------

__device__ __forceinline__ float coeff(int k, const unsigned* Gp, const float* gate,
                                       const float* sv, float C)
{
    if (k < 500) {
        const int g = k / 50, rb = k - g * 50;
        const unsigned w = Gp[rb >> 1];
        const unsigned bits = (rb & 1) ? (w & 0xffff0000u) : (w << 16);
        return gate[g] * __uint_as_float(bits);
    } else if (k < 560) {
        const int jj = k - 500;
        return gate[jj / 6] * sv[jj - (jj / 6) * 6];
    } else if (k < 570) {
        return C * gate[k - 560];
    } else if (k < 580) {
        return gate[k - 570];
    }
    return 0.0f;
}

__global__ void __launch_bounds__(256, 2) k_edge(
    const float* __restrict__ edge_vec,
    const int* __restrict__ perm, const int* __restrict__ blk2z,
    const float* __restrict__ tpar,
    const bf16* __restrict__ PTc, const bf16* __restrict__ Hjb,
    float* __restrict__ gates_ws, float* __restrict__ evb, bf16* __restrict__ eo)
{
    __shared__ __align__(16) bf16 Bs[(NLDSC + 1) * 2048];   // 61440 B

    const int t    = threadIdx.x;
    const int wid  = t >> 6;
    const int lane = t & 63;
    const int er   = lane & 31;
    const int kh   = lane >> 5;
    const bool khb = (kh != 0);
    const int base = blockIdx.x * BE;
    const int pid  = base + wid * 32 + er;

    if (perm[base] < 0) return;                 // all-dummy block (uniform)

    const int zb  = blk2z[blockIdx.x];
    const int eid = perm[pid];

    // ---- stage LDS chunks (loads first; latency hides under scalar math) ----
    const float4* PTc4 = (const float4*)PTc;
    float4 stg[NLDSC];
#pragma unroll
    for (int i = 0; i < NLDSC; ++i) stg[i] = PTc4[t + i * 256];
    const float4 hv = ((const float4*)(Hjb + (size_t)zb * 2048))[t];

    // ---- per-edge scalars ----
    float gate[NG], sv[6];
    float d = 1.0f, C = 0.0f, vx = 0.f, vy = 0.f, vz = 0.f;
    if (eid >= 0) {
        vx = edge_vec[eid * 3]; vy = edge_vec[eid * 3 + 1]; vz = edge_vec[eid * 3 + 2];
        d = sqrtf(vx * vx + vy * vy + vz * vz);
        C = (d < 5.0f) ? 0.5f * (__cosf(d * 0.6283185307179586f) + 1.0f) : 0.0f;
        float m = -3.0e38f;
#pragma unroll
        for (int g = 0; g < NG; ++g) {
            float r = 1.0f / fmaxf(fabsf(d - tpar[g]), 1e-8f);
            gate[g] = r; m = fmaxf(m, r);
        }
        float ss = 0.f;
#pragma unroll
        for (int g = 0; g < NG; ++g) { float ex = __expf(gate[g] - m); gate[g] = ex; ss += ex; }
        const float inv = 1.0f / ss;
#pragma unroll
        for (int g = 0; g < NG; ++g) gate[g] *= inv;
        const float d2 = d * d;
        sv[0] = d2; sv[1] = d2 * d; sv[2] = d2 * d2;
        sv[3] = sqrtf(d); sv[4] = __logf(d); sv[5] = d;
    } else {
#pragma unroll
        for (int g = 0; g < NG; ++g) gate[g] = 0.f;
#pragma unroll
        for (int m2 = 0; m2 < 6; ++m2) sv[m2] = 0.f;
    }

    // ---- packed Gaussian table (bf16 pairs, C folded in): 25 VGPRs ----
    unsigned Gp[25];
#pragma unroll
    for (int p = 0; p < 25; ++p) {
        const float t0 = d - (float)(2 * p) * DELTA_F;
        const float t1 = t0 - DELTA_F;
        const float g0 = C * __expf(-48.02f * t0 * t0);
        const float g1 = C * __expf(-48.02f * t1 * t1);
        Gp[p] = pack2bf(g0, g1);
    }

    if (kh == 0 && eid >= 0) {
        float* gw = gates_ws + (size_t)pid * 12;
#pragma unroll
        for (int g = 0; g < NG; ++g) gw[g] = gate[g];
        const float invd = 1.0f / d;
        *(float4*)(evb + (size_t)pid * 4) =
            make_float4(vx * invd, vy * invd, vz * invd, 0.0f);
    }

    // ---- write staged LDS, single barrier ----
    {
        float4* dst = (float4*)Bs;
#pragma unroll
        for (int i = 0; i < NLDSC; ++i) dst[t + i * 256] = stg[i];
        dst[t + NLDSC * 256] = hv;
    }
    __syncthreads();

    f32x16 acc0 = {}, acc1 = {}, acc2 = {}, acc3 = {};
    const int lanoff = kh * 1024 + er * 8;
    const bf16* Lp = Bs + lanoff;
    const bf16* Gb = PTc + lanoff;

#define MFMA4(AV, B0, B1, B2, B3) do { \
        acc0 = __builtin_amdgcn_mfma_f32_32x32x16_bf16(AV, B0, acc0, 0, 0, 0); \
        acc1 = __builtin_amdgcn_mfma_f32_32x32x16_bf16(AV, B1, acc1, 0, 0, 0); \
        acc2 = __builtin_amdgcn_mfma_f32_32x32x16_bf16(AV, B2, acc2, 0, 0, 0); \
        acc3 = __builtin_amdgcn_mfma_f32_32x32x16_bf16(AV, B3, acc3, 0, 0, 0); \
    } while (0)
#define LDB(P, V0, V1, V2, V3) \
        const bf16x8 V0 = *(const bf16x8*)(P); \
        const bf16x8 V1 = *(const bf16x8*)((P) + 256); \
        const bf16x8 V2 = *(const bf16x8*)((P) + 512); \
        const bf16x8 V3 = *(const bf16x8*)((P) + 768);

    // ---- Hj K-step (gate coefficients) ----
    {
        bf16x8 av;
#pragma unroll
        for (int j = 0; j < 8; ++j) {
            const float va = gate[j];
            const float vb = (j < 2) ? gate[8 + j] : 0.0f;
            av[j] = (bf16)(khb ? vb : va);
        }
        LDB(Lp + NLDSC * 2048, b0, b1, b2, b3);
        MFMA4(av, b0, b1, b2, b3);
    }

    // ---- prefetch first two global chunks ----
    bf16x8 c0, c1, c2, c3, n0, n1, n2, n3;
    {
        const bf16* bp = Gb + NLDSC * 2048;
        c0 = *(const bf16x8*)(bp);       c1 = *(const bf16x8*)(bp + 256);
        c2 = *(const bf16x8*)(bp + 512); c3 = *(const bf16x8*)(bp + 768);
    }
    {
        const bf16* bp = Gb + (NLDSC + 1) * 2048;
        n0 = *(const bf16x8*)(bp);       n1 = *(const bf16x8*)(bp + 256);
        n2 = *(const bf16x8*)(bp + 512); n3 = *(const bf16x8*)(bp + 768);
    }

    // ---- LDS chunks, no barriers ----
#pragma unroll
    for (int ks = 0; ks < NLDSC; ++ks) {
        bf16x8 av;
#pragma unroll
        for (int j = 0; j < 8; ++j) {
            const float va = coeff(ks * 16 + j,     Gp, gate, sv, C);
            const float vb = coeff(ks * 16 + 8 + j, Gp, gate, sv, C);
            av[j] = (bf16)(khb ? vb : va);
        }
        LDB(Lp + ks * 2048, b0, b1, b2, b3);
        MFMA4(av, b0, b1, b2, b3);
    }

    // ---- global chunks, depth-2 register prefetch ----
#pragma unroll
    for (int ks = NLDSC; ks < 37; ++ks) {
        const bf16x8 m0 = c0, m1 = c1, m2 = c2, m3 = c3;
        c0 = n0; c1 = n1; c2 = n2; c3 = n3;
        if (ks + 2 <= 36) {
            const bf16* bp = Gb + (size_t)(ks + 2) * 2048;
            n0 = *(const bf16x8*)(bp);       n1 = *(const bf16x8*)(bp + 256);
            n2 = *(const bf16x8*)(bp + 512); n3 = *(const bf16x8*)(bp + 768);
        }
        bf16x8 av;
#pragma unroll
        for (int j = 0; j < 8; ++j) {
            const float va = coeff(ks * 16 + j,     Gp, gate, sv, C);
            const float vb = coeff(ks * 16 + 8 + j, Gp, gate, sv, C);
            av[j] = (bf16)(khb ? vb : va);
        }
        MFMA4(av, m0, m1, m2, m3);
    }
#undef MFMA4
#undef LDB

    // ---- epilogue: block-local rows, bf16 stores ----
    bf16* eor = eo + (size_t)(base + wid * 32) * 128 + er;
#pragma unroll
    for (int r = 0; r < 16; ++r) {
        const int crow = (r & 3) + 8 * (r >> 2) + 4 * kh;
        bf16* p = eor + (size_t)crow * 128;
        p[0]  = (bf16)acc0[r];
        p[32] = (bf16)acc1[r];
        p[64] = (bf16)acc2[r];
        p[96] = (bf16)acc3[r];
    }
}

// ---------------- gather: lane-split gate sums + exact Hi fold ----------

__global__ void __launch_bounds__(256) k_gather(
    const bf16* __restrict__ eo, const float* __restrict__ evb,
    const float* __restrict__ gates_ws,
    const int* __restrict__ startp, const int* __restrict__ cnt,
    const int* __restrict__ csr, const int* __restrict__ zarr,
    const float* __restrict__ Hi, float* __restrict__ out)
{
    __shared__ float gsum[4][48];
    const int wloc = threadIdx.x >> 6;
    const int atom = blockIdx.x * 4 + wloc;
    const int lane = threadIdx.x & 63;
    if (atom >= NATOMS) return;
    const int s = startp[atom], len = cnt[atom];
    const unsigned* eo32 = (const unsigned*)eo;
    const float4* ev4 = (const float4*)evb;

    // lane roles for gate sums: lanes 0..39 own (comp = lane/10, g = lane%10)
    const int comp = lane / 10;
    const int gidx = lane - comp * 10;
    const bool gl = (lane < 40);
    float gacc = 0.0f;

    float a0 = 0, a1 = 0, v00 = 0, v01 = 0, v10 = 0, v11 = 0, v20 = 0, v21 = 0;

#define ACCE(PID, EV, U) do { \
        const float evc = (comp == 1) ? EV.x : (comp == 2) ? EV.y : (comp == 3) ? EV.z : 1.0f; \
        if (gl) gacc += evc * gates_ws[(size_t)(PID) * 12 + gidx]; \
        const float y0 = __uint_as_float((U) << 16); \
        const float y1 = __uint_as_float((U) & 0xffff0000u); \
        a0 += y0; a1 += y1; \
        v00 += EV.x * y0; v01 += EV.x * y1; \
        v10 += EV.y * y0; v11 += EV.y * y1; \
        v20 += EV.z * y0; v21 += EV.z * y1; \
    } while (0)

    int i = 0;
    for (; i + 4 <= len; i += 4) {
        const int p0 = csr[s + i],     p1 = csr[s + i + 1];
        const int p2 = csr[s + i + 2], p3 = csr[s + i + 3];
        const float4 e0 = ev4[p0], e1 = ev4[p1], e2 = ev4[p2], e3 = ev4[p3];
        const unsigned u0 = eo32[(size_t)p0 * 64 + lane];
        const unsigned u1 = eo32[(size_t)p1 * 64 + lane];
        const unsigned u2 = eo32[(size_t)p2 * 64 + lane];
        const unsigned u3 = eo32[(size_t)p3 * 64 + lane];
        ACCE(p0, e0, u0);
        ACCE(p1, e1, u1);
        ACCE(p2, e2, u2);
        ACCE(p3, e3, u3);
    }
    for (; i < len; ++i) {
        const int p0 = csr[s + i];
        const float4 e0 = ev4[p0];
        const unsigned u0 = eo32[(size_t)p0 * 64 + lane];
        ACCE(p0, e0, u0);
    }
#undef ACCE

    if (gl) gsum[wloc][comp * 10 + gidx] = gacc;   // same-wave write->read, no barrier

    const float* Hrow = Hi + (size_t)zarr[atom] * 1280;
#pragma unroll
    for (int g = 0; g < NG; ++g) {
        const float gs = gsum[wloc][g];
        const float e0 = gsum[wloc][10 + g];
        const float e1 = gsum[wloc][20 + g];
        const float e2 = gsum[wloc][30 + g];
        const float2 h2 = *(const float2*)(Hrow + g * 128 + 2 * lane);
        a0  += gs * h2.x;  a1  += gs * h2.y;
        v00 += e0 * h2.x;  v01 += e0 * h2.y;
        v10 += e1 * h2.x;  v11 += e1 * h2.y;
        v20 += e2 * h2.x;  v21 += e2 * h2.y;
    }
    float* ao = out + (size_t)atom * 128;
    *(float2*)(ao + 2 * lane) = make_float2(a0, a1);
    float* vp = out + OUT_VEC + (size_t)atom * 384;
    *(float2*)(vp + 2 * lane)       = make_float2(v00, v01);
    *(float2*)(vp + 128 + 2 * lane) = make_float2(v10, v11);
    *(float2*)(vp + 256 + 2 * lane) = make_float2(v20, v21);
}

// ---------------- launch ----------------

extern "C" void kernel_launch(void* const* d_in, const int* in_sizes, int n_in,
                              void* d_out, int out_size, void* d_ws, size_t ws_size,
                              hipStream_t stream)
{
    const int*   z        = (const int*)d_in[0];
    const float* pos      = (const float*)d_in[1];
    const int*   batch    = (const int*)d_in[2];
    const int*   esrc     = (const int*)d_in[3];
    const int*   edst     = esrc + NEDGES;
    const float* edge_vec = (const float*)d_in[4];
    const float* emb      = (const float*)d_in[5];
    const float* W_dist   = (const float*)d_in[6];
    const float* b_dist   = (const float*)d_in[7];
    const float* W_dt     = (const float*)d_in[8];
    const float* b_dt     = (const float*)d_in[9];
    const float* W_ai     = (const float*)d_in[10];
    const float* b_ai     = (const float*)d_in[11];
    const float* W_aj     = (const float*)d_in[12];
    const float* b_aj     = (const float*)d_in[13];
    const float* W_gamma  = (const float*)d_in[14];
    const float* b_gamma  = (const float*)d_in[15];
    const float* W_exp    = (const float*)d_in[16];
    const float* b_exp    = (const float*)d_in[17];
    const float* tpar     = (const float*)d_in[18];

    float* out = (float*)d_out;
    float* W   = (float*)d_ws;

    const float* Wg1 = W_gamma;
    const float* Wg2 = W_gamma + 256 * 256;
    const float* Wg3 = W_gamma + 512 * 256;

    float* M1 = W + WS_M1;
    float* M0 = W + WS_M0;
    float* c0 = W + WS_C0;
    float* M2 = W + WS_M2;
    float* cc = W + WS_CC;
    float* Ai = W + WS_AI;
    float* Aj = W + WS_AJ;
    float* Gi = W + WS_GI;
    float* Gj = W + WS_GJ;
    float* Hi = W + WS_HI;
    bf16*  Hjb = (bf16*)(W + WS_HJB);
    bf16*  PTc = (bf16*)(W + WS_PTC);
    float* gates = W + WS_GT;
    float* evb   = W + WS_EV;
    bf16*  eo    = (bf16*)(W + WS_EO);
    int*   I     = (int*)(W + WS_I);
    int* cnt    = I + I_CNT;
    int* startp = I + I_START;
    int* cursor = I + I_CUR;
    int* csr    = I + I_CSR;
    int* zbins  = I + I_ZB;
    int* zcur   = I + I_ZC;
    int* b2z    = I + I_B2Z;
    int* bsum   = I + I_BSUM;
    int* boffs  = I + I_BOFF;
    int* perm   = I + I_PERM;

    k0<<<1024, 256, 0, stream>>>(cnt, zbins, perm, (int*)Hjb);
    kA<<<2613, 256, 0, stream>>>(W_dt, b_dt, b_gamma, Wg3, M1, M2, cc,
                                 emb, W_ai, b_ai, W_aj, b_aj, Ai, Aj,
                                 esrc, edst, z, cnt, zbins, pos, batch, out);
    kBD1<<<300, 1024, 0, stream>>>(W_dist, b_dist, M1, M0, c0, Ai, Aj, Wg1, Wg2,
                                   Gi, Gj, cnt, startp, bsum);
    kCD2<<<843, 128, 0, stream>>>(Gi, Gj, W_exp, Hi, Hjb, M0, M2, c0, cc, b_exp,
                                  PTc, bsum, boffs, zbins, zcur, b2z);
    kD3<<<49, 1024, 0, stream>>>(boffs, startp, cursor);
    k_zfill<<<(NEDGES + ZF_EPB - 1) / ZF_EPB, 256, 0, stream>>>(edst, z, esrc, zcur, cursor, perm, csr);

    k_edge<<<NBLK, 256, 0, stream>>>(edge_vec, perm, b2z, tpar, PTc, Hjb, gates, evb, eo);
    k_gather<<<(NATOMS + 3) / 4, 256, 0, stream>>>(eo, evb, gates, startp, cnt, csr, z, Hi, out);
}